// Round 3
// baseline (556.685 us; speedup 1.0000x reference)
//
#include <hip/hip_runtime.h>
#include <hip/hip_bf16.h>
#include <stdint.h>

#define T_TOK 1024
#define H_DIM 1024
#define I_DIM 2816
#define E_NUM 8
#define SLOTCAP 512   // max tokens per expert (typ ~256, binomial sigma ~15)

typedef __attribute__((ext_vector_type(8))) short bf16x8;
typedef __attribute__((ext_vector_type(4))) float f32x4;

struct Meta { int tiles[E_NUM]; int offs[E_NUM]; };   // tiles in 128-row units

__device__ __forceinline__ unsigned short f2b(float f) {
    unsigned u = __float_as_uint(f);
    u += 0x7fffu + ((u >> 16) & 1u);   // RNE
    return (unsigned short)(u >> 16);
}
__device__ __forceinline__ ushort4 f2b4(float4 v) {
    ushort4 o; o.x = f2b(v.x); o.y = f2b(v.y); o.z = f2b(v.z); o.w = f2b(v.w); return o;
}
// 8 fp32 -> bf16x8 via packed cvt (v_cvt_pk_bf16_f32)
__device__ __forceinline__ bf16x8 cvt8(float4 a, float4 b) {
    union { bf16x8 v; __hip_bfloat162 h[4]; } u;
    u.h[0] = __float22bfloat162_rn(make_float2(a.x, a.y));
    u.h[1] = __float22bfloat162_rn(make_float2(a.z, a.w));
    u.h[2] = __float22bfloat162_rn(make_float2(b.x, b.y));
    u.h[3] = __float22bfloat162_rn(make_float2(b.z, b.w));
    return u.v;
}
__device__ __forceinline__ bf16x8 as_bf16x8(uint4 u) {
    union { uint4 a; bf16x8 b; } x; x.a = u; return x.b;
}

// ---------------- routing ----------------
__global__ void route_kernel(const float* __restrict__ logits,
                             int* __restrict__ tok, float* __restrict__ gate,
                             Meta* __restrict__ meta) {
    __shared__ int cnt[E_NUM];
    const int tid = threadIdx.x;   // token id, blockDim = 1024
    if (tid < E_NUM) cnt[tid] = 0;
    for (int j = tid; j < E_NUM * SLOTCAP; j += 1024) { tok[j] = 0; gate[j] = 0.f; }
    __syncthreads();

    float p[E_NUM];
    const float* lrow = logits + tid * E_NUM;
    float m = -1e30f;
    #pragma unroll
    for (int e = 0; e < E_NUM; ++e) { p[e] = lrow[e]; m = fmaxf(m, p[e]); }
    #pragma unroll
    for (int e = 0; e < E_NUM; ++e) p[e] = __expf(p[e] - m);
    int e0 = 0; float v0 = p[0];
    #pragma unroll
    for (int e = 1; e < E_NUM; ++e) if (p[e] > v0) { v0 = p[e]; e0 = e; }
    int e1 = -1; float v1 = -1.f;
    #pragma unroll
    for (int e = 0; e < E_NUM; ++e) if (e != e0 && p[e] > v1) { v1 = p[e]; e1 = e; }
    const float inv = 1.f / (v0 + v1);
    const float g0 = v0 * inv, g1 = v1 * inv;

    const int p0 = atomicAdd(&cnt[e0], 1);
    const int p1 = atomicAdd(&cnt[e1], 1);
    if (p0 < SLOTCAP) { tok[e0 * SLOTCAP + p0] = tid; gate[e0 * SLOTCAP + p0] = g0; }
    if (p1 < SLOTCAP) { tok[e1 * SLOTCAP + p1] = tid; gate[e1 * SLOTCAP + p1] = g1; }
    __syncthreads();
    if (tid == 0) {
        int off = 0;
        for (int e = 0; e < E_NUM; ++e) {
            int c = cnt[e]; if (c > SLOTCAP) c = SLOTCAP;
            const int t = (c + 127) >> 7;   // 128-row granularity
            meta->tiles[e] = t; meta->offs[e] = off;
            off += t * 128;
        }
    }
}

// ---------------- x fp32 -> bf16 ----------------
__global__ void cvt_x_kernel(const float* __restrict__ x, unsigned short* __restrict__ xb) {
    const int i = blockIdx.x * blockDim.x + threadIdx.x;
    ((ushort4*)xb)[i] = f2b4(((const float4*)x)[i]);
}

// ---------------- GEMM1: act = silu(x@w1^T)*(x@w3^T). No LDS, no barriers. ----------------
// grid (88, 8, 2), block 256 = 4 waves stacking M. Block tile: 256 rows x 32 I-cols.
// Per wave: 64x32 out (mi=4, ni=2 frags), B fragments loaded direct from global fp32.
__launch_bounds__(256)
__global__ void gemm1_kernel(const unsigned short* __restrict__ xb,
                             const float* __restrict__ w1,
                             const float* __restrict__ w3,
                             const int* __restrict__ tok,
                             const Meta* __restrict__ meta,
                             unsigned short* __restrict__ act) {
    const int e = blockIdx.y, mt = blockIdx.z, it = blockIdx.x;
    const int rsize = meta->tiles[e] * 128;
    if (mt * 256 >= rsize) return;
    const int tid = threadIdx.x, wave = tid >> 6, lane = tid & 63;
    const int quad = lane >> 4, l15 = lane & 15;
    const int rbase = mt * 256 + wave * 64;

    // A row base pointers (gathered tokens), frag k-offset quad*8 baked in
    const unsigned short* ap[4];
    #pragma unroll
    for (int mi = 0; mi < 4; ++mi) {
        const int t = tok[e * SLOTCAP + rbase + mi * 16 + l15];
        ap[mi] = xb + (size_t)t * H_DIM + quad * 8;
    }
    // B row pointers (fp32, row-major [I][H]): lane owns row col=it*32+ni*16+l15
    const float *bp1[2], *bp3[2];
    #pragma unroll
    for (int ni = 0; ni < 2; ++ni) {
        const size_t o = ((size_t)e * I_DIM + it * 32 + ni * 16 + l15) * H_DIM + quad * 8;
        bp1[ni] = w1 + o; bp3[ni] = w3 + o;
    }

    f32x4 acc1[4][2], acc3[4][2];
    #pragma unroll
    for (int mi = 0; mi < 4; ++mi)
        #pragma unroll
        for (int ni = 0; ni < 2; ++ni) {
            acc1[mi][ni] = (f32x4){0.f, 0.f, 0.f, 0.f};
            acc3[mi][ni] = (f32x4){0.f, 0.f, 0.f, 0.f};
        }

    uint4 ra[4]; float4 r1[2][2], r3[2][2];
    #pragma unroll
    for (int mi = 0; mi < 4; ++mi) ra[mi] = *(const uint4*)(ap[mi]);
    #pragma unroll
    for (int ni = 0; ni < 2; ++ni) {
        r1[ni][0] = *(const float4*)(bp1[ni]);     r1[ni][1] = *(const float4*)(bp1[ni] + 4);
        r3[ni][0] = *(const float4*)(bp3[ni]);     r3[ni][1] = *(const float4*)(bp3[ni] + 4);
    }

    const int NK = H_DIM / 32;   // 32
    for (int ks = 0; ks < NK; ++ks) {
        bf16x8 a[4], b1[2], b3[2];
        #pragma unroll
        for (int mi = 0; mi < 4; ++mi) a[mi] = as_bf16x8(ra[mi]);
        #pragma unroll
        for (int ni = 0; ni < 2; ++ni) {
            b1[ni] = cvt8(r1[ni][0], r1[ni][1]);
            b3[ni] = cvt8(r3[ni][0], r3[ni][1]);
        }
        if (ks + 1 < NK) {
            const int ko = (ks + 1) * 32;
            #pragma unroll
            for (int mi = 0; mi < 4; ++mi) ra[mi] = *(const uint4*)(ap[mi] + ko);
            #pragma unroll
            for (int ni = 0; ni < 2; ++ni) {
                r1[ni][0] = *(const float4*)(bp1[ni] + ko); r1[ni][1] = *(const float4*)(bp1[ni] + ko + 4);
                r3[ni][0] = *(const float4*)(bp3[ni] + ko); r3[ni][1] = *(const float4*)(bp3[ni] + ko + 4);
            }
        }
        #pragma unroll
        for (int mi = 0; mi < 4; ++mi)
            #pragma unroll
            for (int ni = 0; ni < 2; ++ni) {
                acc1[mi][ni] = __builtin_amdgcn_mfma_f32_16x16x32_bf16(a[mi], b1[ni], acc1[mi][ni], 0, 0, 0);
                acc3[mi][ni] = __builtin_amdgcn_mfma_f32_16x16x32_bf16(a[mi], b3[ni], acc3[mi][ni], 0, 0, 0);
            }
    }

    const int opad = meta->offs[e];
    #pragma unroll
    for (int mi = 0; mi < 4; ++mi)
        #pragma unroll
        for (int ni = 0; ni < 2; ++ni)
            #pragma unroll
            for (int rr = 0; rr < 4; ++rr) {
                const int lrow = rbase + mi * 16 + quad * 4 + rr;
                if (lrow < rsize) {
                    const float v1 = acc1[mi][ni][rr], v3 = acc3[mi][ni][rr];
                    const float s = v1 / (1.f + __expf(-v1)) * v3;
                    act[(size_t)(opad + lrow) * I_DIM + it * 32 + ni * 16 + l15] = f2b(s);
                }
            }
}

// ---------------- GEMM2: out[t] += gate * (act @ w2^T). No LDS, no barriers. ----------------
// grid (32, 8, 2), block 256 = 4 waves stacking M. Block tile: 256 rows x 32 H-cols, K=2816.
__launch_bounds__(256)
__global__ void gemm2_kernel(const unsigned short* __restrict__ act,
                             const float* __restrict__ w2,
                             const int* __restrict__ tok,
                             const float* __restrict__ gate,
                             const Meta* __restrict__ meta,
                             float* __restrict__ out) {
    const int e = blockIdx.y, mt = blockIdx.z, it = blockIdx.x;
    const int rsize = meta->tiles[e] * 128;
    if (mt * 256 >= rsize) return;
    const int tid = threadIdx.x, wave = tid >> 6, lane = tid & 63;
    const int quad = lane >> 4, l15 = lane & 15;
    const int rbase = mt * 256 + wave * 64;
    const int opad = meta->offs[e];

    const unsigned short* ap[4];
    #pragma unroll
    for (int mi = 0; mi < 4; ++mi)
        ap[mi] = act + (size_t)(opad + rbase + mi * 16 + l15) * I_DIM + quad * 8;
    const float* bp[2];
    #pragma unroll
    for (int ni = 0; ni < 2; ++ni)
        bp[ni] = w2 + ((size_t)e * H_DIM + it * 32 + ni * 16 + l15) * I_DIM + quad * 8;

    f32x4 acc[4][2];
    #pragma unroll
    for (int mi = 0; mi < 4; ++mi)
        #pragma unroll
        for (int ni = 0; ni < 2; ++ni) acc[mi][ni] = (f32x4){0.f, 0.f, 0.f, 0.f};

    uint4 ra[4]; float4 rb[2][2];
    #pragma unroll
    for (int mi = 0; mi < 4; ++mi) ra[mi] = *(const uint4*)(ap[mi]);
    #pragma unroll
    for (int ni = 0; ni < 2; ++ni) {
        rb[ni][0] = *(const float4*)(bp[ni]); rb[ni][1] = *(const float4*)(bp[ni] + 4);
    }

    const int NK = I_DIM / 32;   // 88
    for (int ks = 0; ks < NK; ++ks) {
        bf16x8 a[4], b[2];
        #pragma unroll
        for (int mi = 0; mi < 4; ++mi) a[mi] = as_bf16x8(ra[mi]);
        #pragma unroll
        for (int ni = 0; ni < 2; ++ni) b[ni] = cvt8(rb[ni][0], rb[ni][1]);
        if (ks + 1 < NK) {
            const int ko = (ks + 1) * 32;
            #pragma unroll
            for (int mi = 0; mi < 4; ++mi) ra[mi] = *(const uint4*)(ap[mi] + ko);
            #pragma unroll
            for (int ni = 0; ni < 2; ++ni) {
                rb[ni][0] = *(const float4*)(bp[ni] + ko); rb[ni][1] = *(const float4*)(bp[ni] + ko + 4);
            }
        }
        #pragma unroll
        for (int mi = 0; mi < 4; ++mi)
            #pragma unroll
            for (int ni = 0; ni < 2; ++ni)
                acc[mi][ni] = __builtin_amdgcn_mfma_f32_16x16x32_bf16(a[mi], b[ni], acc[mi][ni], 0, 0, 0);
    }

    #pragma unroll
    for (int mi = 0; mi < 4; ++mi)
        #pragma unroll
        for (int rr = 0; rr < 4; ++rr) {
            const int lrow = rbase + mi * 16 + quad * 4 + rr;
            if (lrow < rsize) {
                const int t = tok[e * SLOTCAP + lrow];
                const float g = gate[e * SLOTCAP + lrow];
                #pragma unroll
                for (int ni = 0; ni < 2; ++ni)
                    atomicAdd(&out[(size_t)t * H_DIM + it * 32 + ni * 16 + l15], g * acc[mi][ni][rr]);
            }
        }
}

extern "C" void kernel_launch(void* const* d_in, const int* in_sizes, int n_in,
                              void* d_out, int out_size, void* d_ws, size_t ws_size,
                              hipStream_t stream) {
    const float* x      = (const float*)d_in[0];
    const float* logits = (const float*)d_in[1];
    const float* w1     = (const float*)d_in[2];
    const float* w3     = (const float*)d_in[3];
    const float* w2     = (const float*)d_in[4];
    float* out = (float*)d_out;

    char* ws = (char*)d_ws;
    int*   tok  = (int*)ws;                                   // 8*512 ints  (16 KB)
    float* gate = (float*)(ws + 16384);                       // 8*512 floats(16 KB)
    Meta*  meta = (Meta*)(ws + 32768);
    unsigned short* xb  = (unsigned short*)(ws + 65536);      // 2 MB
    unsigned short* act = (unsigned short*)(ws + 65536 + 2097152); // up to 4096 x 2816 bf16 (23 MB)

    hipMemsetAsync(d_out, 0, (size_t)T_TOK * H_DIM * sizeof(float), stream);
    route_kernel<<<1, 1024, 0, stream>>>(logits, tok, gate, meta);
    cvt_x_kernel<<<T_TOK * H_DIM / 4 / 256, 256, 0, stream>>>(x, xb);
    gemm1_kernel<<<dim3(I_DIM / 32, E_NUM, 2), 256, 0, stream>>>(xb, w1, w3, tok, meta, act);
    gemm2_kernel<<<dim3(H_DIM / 32, E_NUM, 2), 256, 0, stream>>>(act, w2, tok, gate, meta, out);
}